// Round 11
// baseline (707.632 us; speedup 1.0000x reference)
//
#include <hip/hip_runtime.h>
#include <cstdint>

#define NPIX  1024
#define NH    992
#define NEDGE 1984
#define NSORT 2048
#define NGRP  31
#define HFS   4300
#define POOLN (NPIX + 2*HFS)   // 9624 u32 entries per phase

typedef unsigned long long u64;
typedef unsigned int u32;

// root_ pack (labeled live sets only; 0 == dead/unlabeled):
// sL[0,11) | off[11,25) | len[25,36) | cap[36,47)
static __device__ __forceinline__ u64 packRoot(int sL,int off,int len,int cap){
    return (u64)(u32)(sL & 0x7FF) | ((u64)(u32)(off & 0x3FFF) << 11) |
           ((u64)(u32)(len & 0x7FF) << 25) | ((u64)(u32)(cap & 0x7FF) << 36);
}
#define R_SL(R)  ((int)((R) & 0x7FF))
#define R_OFF(R) ((int)(((R)>>11) & 0x3FFF))
#define R_LEN(R) ((int)(((R)>>25) & 0x7FF))
#define R_CAP(R) ((int)(((R)>>36) & 0x7FF))

static __device__ __forceinline__ int rdl(int v, int l){ return __builtin_amdgcn_readlane(v, l); }

static __device__ __forceinline__ u64 sxor64(u64 v, int m){
    u32 lo = (u32)__shfl_xor((int)(v & 0xFFFFFFFFull), m, 64);
    u32 hi = (u32)__shfl_xor((int)(v >> 32), m, 64);
    return ((u64)hi << 32) | lo;
}

// in-register compare-exchange: x at lower global index
#define CE(x, y, up) { u64 _a=(x), _b=(y); bool _lt=(_a<_b); \
    u64 _mn=_lt?_a:_b, _mx=_lt?_b:_a; (x)=(up)?_mn:_mx; (y)=(up)?_mx:_mn; }
// cross-lane compare-exchange via shfl_xor
#define CEX(x, xm, keepmin) { u64 _p=sxor64((x),(xm)); bool _lt=((x)<_p); \
    u64 _mn=_lt?(x):_p, _mx=_lt?_p:(x); (x)=(keepmin)?_mn:_mx; }

static __device__ __forceinline__ int wredi(int v){
    #pragma unroll
    for (int o = 32; o > 0; o >>= 1) v += __shfl_xor(v, o, 64);
    return v;
}
static __device__ __forceinline__ float wredf(float v){
    #pragma unroll
    for (int o = 32; o > 0; o >>= 1) v += __shfl_xor(v, o, 64);
    return v;
}

// comp-table extraction: uniform pixel px -> its comp id (uniform).
// c0..c15 are per-lane registers; reg index px>>6 is uniform -> cndmask tree.
#define EXTRACT(res, px) { int _ri=(px)>>6, _ol=(px)&63; \
  int _a0=(_ri&1)?c1:c0,  _a1=(_ri&1)?c3:c2,  _a2=(_ri&1)?c5:c4,  _a3=(_ri&1)?c7:c6; \
  int _a4=(_ri&1)?c9:c8,  _a5=(_ri&1)?c11:c10,_a6=(_ri&1)?c13:c12,_a7=(_ri&1)?c15:c14; \
  int _b0=(_ri&2)?_a1:_a0, _b1=(_ri&2)?_a3:_a2, _b2=(_ri&2)?_a5:_a4, _b3=(_ri&2)?_a7:_a6; \
  int _e0=(_ri&4)?_b1:_b0, _e1=(_ri&4)?_b3:_b2; \
  int _d =(_ri&8)?_e1:_e0; \
  (res) = rdl(_d, _ol); }

#define RELAB(L,W) { \
  c0 =(c0 ==(L))?(W):c0;  c1 =(c1 ==(L))?(W):c1;  c2 =(c2 ==(L))?(W):c2;  c3 =(c3 ==(L))?(W):c3; \
  c4 =(c4 ==(L))?(W):c4;  c5 =(c5 ==(L))?(W):c5;  c6 =(c6 ==(L))?(W):c6;  c7 =(c7 ==(L))?(W):c7; \
  c8 =(c8 ==(L))?(W):c8;  c9 =(c9 ==(L))?(W):c9;  c10=(c10==(L))?(W):c10; c11=(c11==(L))?(W):c11; \
  c12=(c12==(L))?(W):c12; c13=(c13==(L))?(W):c13; c14=(c14==(L))?(W):c14; c15=(c15==(L))?(W):c15; }

__global__ __launch_bounds__(128) void malis_kernel(
    const float* __restrict__ pred,
    const float* __restrict__ target,
    const float* __restrict__ lr_p,
    const float* __restrict__ lrp_p,
    float* __restrict__ out)
{
    const int tid  = threadIdx.x;
    const int lane = tid & 63;
    const int wv   = tid >> 6;        // wave 0: negative pass, wave 1: positive pass
    const int bid  = blockIdx.x;
    const int bb   = bid >> 6;
    const int win  = bid & 63;
    const int wy   = win >> 3, wx = win & 7;
    const int base = bb * 65536 + (wy * 32) * 256 + wx * 32;

    // ---- LDS (~156.1 KB; 1 block/CU) ----
    __shared__ __align__(16) u32 Ks[2][NSORT]; // 16384 rank->edge, then FE list (in place)
    __shared__ u64   root[2][NPIX];         // 16384 labeled-set metadata (weighted merges)
    __shared__ float predL[NPIX];           // 4096
    __shared__ u32   eab[NEDGE];            // 7936  a | b<<16
    __shared__ u32   poolS[2][POOLN];       // 76992 label-count arrays {lab<<16|cnt}
    __shared__ u32   Q[2][NPIX];            // 8192  weighted-merge edge ids
    __shared__ float Qw[2][NPIX];           // 8192  weights (minE claim array during Boruvka)
    __shared__ unsigned short rnk[2][NEDGE];// 7936  edge -> rank
    __shared__ short seg[NPIX];             // 2048
    __shared__ short par[2][NPIX];          // 4096  (Boruvka only)
    __shared__ short H[2][NPIX + 1];        // 4100  (slow-path histogram only)
    __shared__ u32   fb[2][64];             // 512   forest-edge bitmap
    __shared__ unsigned char tgtL[NPIX];    // 1024
    __shared__ unsigned char gtcL[NEDGE];   // 1984
    __shared__ int   flags[2];

    // early scratch overlaid on poolS (dead until UF init)
    unsigned char* mA    = (unsigned char*)poolS;
    unsigned char* mB    = mA + NPIX;
    short*         labId = (short*)(mA + 2 * NPIX);

    // ---- load window ----
    for (int i = tid; i < NPIX; i += 128) {
        int r = i >> 5, c = i & 31;
        float pv = pred[base + r * 256 + c];
        float tv = target[base + r * 256 + c];
        predL[i] = pv;
        tgtL[i]  = (unsigned char)tv;
        mA[i]    = (tv == 0.0f) ? 1 : 0;
    }
    if (tid == 0) flags[1] = 0;
    __syncthreads();

    // ---- dilate 5x (4-neighborhood) ----
    unsigned char* srcm = mA;
    unsigned char* dstm = mB;
    for (int it = 0; it < 5; ++it) {
        for (int i = tid; i < NPIX; i += 128) {
            int r = i >> 5, c = i & 31;
            unsigned char v = srcm[i];
            if (r > 0)  v |= srcm[i - 32];
            if (r < 31) v |= srcm[i + 32];
            if (c > 0)  v |= srcm[i - 1];
            if (c < 31) v |= srcm[i + 1];
            dstm[i] = v;
        }
        __syncthreads();
        unsigned char* t2 = srcm; srcm = dstm; dstm = t2;
    }

    // ---- CCL (8-conn) on fg = !dilated ----
    for (int i = tid; i < NPIX; i += 128)
        seg[i] = srcm[i] ? (short)-1 : (short)i;
    __syncthreads();

    for (;;) {
        if (tid == 0) flags[0] = 0;
        __syncthreads();
        bool any = false;
        for (int i = tid; i < NPIX; i += 128) {
            int cur = seg[i];
            if (cur < 0) continue;
            int r = i >> 5, c = i & 31;
            int m = cur;
            if (r > 0) {
                if (c > 0)  { int t = seg[i - 33]; if (t >= 0 && t < m) m = t; }
                { int t = seg[i - 32]; if (t >= 0 && t < m) m = t; }
                if (c < 31) { int t = seg[i - 31]; if (t >= 0 && t < m) m = t; }
            }
            if (c > 0)  { int t = seg[i - 1]; if (t >= 0 && t < m) m = t; }
            if (c < 31) { int t = seg[i + 1]; if (t >= 0 && t < m) m = t; }
            if (r < 31) {
                if (c > 0)  { int t = seg[i + 31]; if (t >= 0 && t < m) m = t; }
                { int t = seg[i + 32]; if (t >= 0 && t < m) m = t; }
                if (c < 31) { int t = seg[i + 33]; if (t >= 0 && t < m) m = t; }
            }
            #pragma unroll
            for (int t2 = 0; t2 < 6; ++t2) {
                int s2 = seg[m];
                if (s2 >= 0 && s2 < m) m = s2; else break;
            }
            if (m < cur) { seg[i] = (short)m; any = true; }
        }
        if (any) flags[0] = 1;
        __syncthreads();
        if (flags[0] == 0) break;
        __syncthreads();
    }

    // compact label ids: seg -> 0 (bg) or 1..K
    for (int i = tid; i < NPIX; i += 128)
        if (seg[i] == (short)i) labId[i] = (short)atomicAdd(&flags[1], 1);
    __syncthreads();
    for (int i = tid; i < NPIX; i += 128) {
        short s2 = seg[i];
        seg[i] = (s2 < 0) ? (short)0 : (short)(labId[s2] + 1);
    }

    // ---- edges (reference order: 992 horizontal then 992 vertical) ----
    for (int e = tid; e < NEDGE; e += 128) {
        int a, b2;
        if (e < NH) { int r = e / 31, c = e - r * 31; a = r * 32 + c; b2 = a + 1; }
        else        { int q = e - NH; int r = q >> 5, c = q & 31; a = r * 32 + c; b2 = a + 32; }
        eab[e]   = (u32)a | ((u32)b2 << 16);
        gtcL[e]  = (unsigned char)(tgtL[a] + tgtL[b2]);
    }
    __syncthreads();
    // ======== no block barriers below this line: waves fully decoupled ========

    const int ph = wv;                 // 0 = neg, 1 = pos
    u32*   Ks_   = Ks[ph];
    short* par_  = par[ph];
    u64*   root_ = root[ph];
    u32*   pool_ = poolS[ph];
    short* H_    = H[ph];
    u32*   Q_    = Q[ph];
    float* Qw_   = Qw[ph];
    u32*   minE_ = (u32*)Qw[ph];       // Boruvka min-edge per root (Qw dead till replay)
    unsigned short* rnk_ = rnk[ph];
    u32*   fb_   = fb[ph];

    // ---- register-resident bitonic sort of 2048 u64 keys ----
    // key = (~bits(cost))<<32 | e ; ascending == (cost desc, idx asc) == ref order
    u64 sk[32];
    #pragma unroll
    for (int r = 0; r < 32; ++r) {
        int e = lane * 32 + r;
        u64 kv = ~0ULL;                       // padding sorts to tail
        if (e < NEDGE) {
            u32 ab = eab[e];
            float cv = predL[ab & 0xFFFF] + predL[ab >> 16];
            int g = gtcL[e];
            if (ph == 0) { if (g > 20) cv = 20.0f; }
            else         { if (g < 10) cv = 0.0f; }
            kv = (((u64)(~__float_as_uint(cv))) << 32) | (u32)e;  // costs >= 0: monotone bits
        }
        sk[r] = kv;
    }
    #pragma unroll
    for (int kk2 = 2; kk2 <= 32; kk2 <<= 1) {
        #pragma unroll
        for (int j = kk2 >> 1; j > 0; j >>= 1) {
            #pragma unroll
            for (int r = 0; r < 32; ++r) {
                if ((r & j) == 0) {
                    bool up = (kk2 == 32) ? ((lane & 1) == 0) : ((r & kk2) == 0);
                    CE(sk[r], sk[r | j], up);
                }
            }
        }
    }
    #pragma unroll
    for (int kk2 = 64; kk2 <= 2048; kk2 <<= 1) {
        const bool up = ((lane & (kk2 >> 5)) == 0);
        #pragma unroll
        for (int j = kk2 >> 1; j >= 32; j >>= 1) {
            const int xm = j >> 5;
            const bool keepmin = (((lane & xm) == 0) == up);
            #pragma unroll
            for (int r = 0; r < 32; ++r) { CEX(sk[r], xm, keepmin); }
        }
        #pragma unroll
        for (int j = 16; j > 0; j >>= 1) {
            #pragma unroll
            for (int r = 0; r < 32; ++r) {
                if ((r & j) == 0) { CE(sk[r], sk[r | j], up); }
            }
        }
    }
    // writeback rank->edge AND scatter edge->rank
    #pragma unroll
    for (int r = 0; r < 32; ++r) {
        u32 lo = (u32)sk[r];
        Ks_[lane * 32 + r] = lo;
        if (lo < NEDGE) rnk_[lo] = (unsigned short)(lane * 32 + r);
    }

    // ---- init: UF, labeled pool sets, labBits, Boruvka scratch ----
    u32 labBits = 0;
    for (int k = 0; k < 16; ++k) {
        int i = k * 64 + lane;
        par_[i] = (short)i;
        short s2 = seg[i];
        if (s2) {
            labBits |= 1u << k;
            root_[i] = packRoot(1, i, 1, 1);
            pool_[i] = ((u32)(unsigned short)s2 << 16) | 1u;
        } else {
            root_[i] = 0;
        }
        H_[i] = 0;
    }
    if (lane == 0) { H_[NPIX] = 0; fb_[62] = 0; fb_[63] = 0; }
    if (lane < 62) fb_[lane] = 0;
    __builtin_amdgcn_wave_barrier();

    // ---- Boruvka: find the greedy forest (= serial-Kruskal merge set) ----
    // Unique ranks => unique MSF == greedy forest. Each round every comp
    // atomicMins its min-rank incident edge; selected edges are forest edges
    // (cut property); hook root->root with 2-cycle tie-break; pointer-jump.
    {
        u32 deadmask = 0;
        for (int round = 0; round < 12; ++round) {
            for (int k = 0; k < 16; ++k) minE_[k * 64 + lane] = ~0u;
            __builtin_amdgcn_wave_barrier();
            bool anyAlive = false;
            for (int j = 0; j < 31; ++j) {
                if ((deadmask >> j) & 1) continue;
                int e = j * 64 + lane;
                u32 ab = eab[e];
                int ra = (int)(ab & 0xFFFF), rb = (int)(ab >> 16);
                for (;;) {
                    int pa = par_[ra], pb = par_[rb];
                    bool fa = (pa != ra), fbb = (pb != rb);
                    if (!fa && !fbb) break;
                    int ga = par_[pa], gb = par_[pb];
                    if (fa)  { par_[ra] = (short)ga; ra = ga; }
                    if (fbb) { par_[rb] = (short)gb; rb = gb; }
                }
                if (ra == rb) { deadmask |= 1u << j; continue; }
                anyAlive = true;
                u32 v = ((u32)rnk_[e] << 11) | (u32)e;
                atomicMin(&minE_[ra], v);
                atomicMin(&minE_[rb], v);
            }
            u64 alv = __ballot(anyAlive);
            __builtin_amdgcn_wave_barrier();
            if (!alv) break;
            // hooking
            for (int k = 0; k < 16; ++k) {
                int i = k * 64 + lane;
                if (par_[i] != (short)i) continue;
                u32 v = minE_[i];
                if (v == ~0u) continue;
                int e = (int)(v & 0x7FF);
                u32 ab = eab[e];
                int ra = (int)(ab & 0xFFFF), rb = (int)(ab >> 16);
                for (;;) { int p = par_[ra]; if (p == ra) break; ra = p; }
                for (;;) { int p = par_[rb]; if (p == rb) break; rb = p; }
                int o = (ra == i) ? rb : ra;
                if (o == i) continue;                 // other side already hooked via e
                u32 vo = minE_[o];
                if (vo == v && i < o) continue;       // 2-cycle tie-break: o hooks to i
                par_[i] = (short)o;
                atomicOr(&fb_[e >> 5], 1u << (e & 31));
            }
            __builtin_amdgcn_wave_barrier();
            // pointer jumping to full compression
            for (int it2 = 0; it2 < 12; ++it2) {
                bool ch = false;
                for (int k = 0; k < 16; ++k) {
                    int p = k * 64 + lane;
                    int q1 = par_[p];
                    int q2 = par_[q1];
                    if (q2 != q1) { par_[p] = (short)q2; ch = true; }
                }
                u64 cb2 = __ballot(ch);
                __builtin_amdgcn_wave_barrier();
                if (!cb2) break;
            }
        }
    }

    // ---- compact forest edges (rank order) in place into Ks_[0..nF) ----
    int nF = 0;
    const u64 ltm = (1ull << lane) - 1;
    for (int g2 = 0; g2 < NGRP; ++g2) {
        u32 e = Ks_[g2 * 64 + lane];
        bool isf = (fb_[e >> 5] >> (e & 31)) & 1u;
        u64 m = __ballot(isf);
        __builtin_amdgcn_wave_barrier();
        int pos = nF + (int)__popcll(m & ltm);
        if (isf) Ks_[pos] = e;                // pos < (g2+1)*64: safe (same-wave order)
        nF += (int)__popcll(m);
    }
    __builtin_amdgcn_wave_barrier();

    // ---- replay forest edges in rank order; comp table in registers ----
    // Every edge merges (no finds / no ballots). Comp id invariant under
    // labeled-wins: id labeled <=> comp contains labels (labBits static).
    u32 bump = NPIX;
    u32 halfEnd = NPIX + HFS;
    int curHalf = 0;

    auto do_gc = [&]() {           // ping-pong compaction; live entries <= 1024 < HFS
        u32 tgt = (curHalf == 0) ? (u32)(NPIX + HFS) : (u32)NPIX;
        u32 nb = tgt;
        for (int c = 0; c < 16; ++c) {
            int i0 = c * 64 + lane;
            bool live = (root_[i0] != 0);
            u64 rbm = __ballot(live);
            while (rbm) {
                int j = __ffsll(rbm) - 1; rbm &= rbm - 1;
                int r = c * 64 + j;
                u64 R = root_[r];
                int len = R_LEN(R);
                int off = R_OFF(R);
                for (int t = lane; t < len; t += 64) {
                    u32 v2 = pool_[off + t];
                    pool_[nb + t] = v2;
                }
                __builtin_amdgcn_wave_barrier();
                if (lane == 0) root_[r] = packRoot(R_SL(R), (int)nb, len, len);
                nb += (u32)len;
            }
        }
        bump = nb;
        halfEnd = tgt + HFS;
        curHalf ^= 1;
    };

    int c0 = lane, c1 = 64 + lane, c2 = 128 + lane, c3 = 192 + lane;
    int c4 = 256 + lane, c5 = 320 + lane, c6 = 384 + lane, c7 = 448 + lane;
    int c8 = 512 + lane, c9 = 576 + lane, c10 = 640 + lane, c11 = 704 + lane;
    int c12 = 768 + lane, c13 = 832 + lane, c14 = 896 + lane, c15 = 960 + lane;

    int qn = 0;
    for (int b0 = 0; b0 < nF; b0 += 64) {
        int idx = b0 + lane;
        int myE = (idx < nF) ? (int)Ks_[idx] : 0;
        u32 myAB = eab[myE];
        int cnt = nF - b0; if (cnt > 64) cnt = 64;
        for (int t = 0; t < cnt; ++t) {
            int e  = rdl(myE, t);
            u32 ab = (u32)rdl((int)myAB, t);
            int a = (int)(ab & 0xFFFF), b = (int)(ab >> 16);
            int ca, cb;
            EXTRACT(ca, a);
            EXTRACT(cb, b);
            u32 lwa = (u32)rdl((int)labBits, ca & 63);
            u32 lwb = (u32)rdl((int)labBits, cb & 63);
            bool lA = (lwa >> (ca >> 6)) & 1u;
            bool lB = (lwb >> (cb >> 6)) & 1u;
            int w_, l_;
            if (lA && lB) {
                // weighted merge: pool-set merge + weight, exact rank order
                int A = ca < cb ? ca : cb;
                int B = ca < cb ? cb : ca;
                w_ = A; l_ = B;
                u64 RA = root_[A], RB = root_[B];
                int sLa = R_SL(RA), sLb = R_SL(RB);
                int lenA = R_LEN(RA), lenB = R_LEN(RB);
                if (bump + (u32)(lenA + lenB + 8) > halfEnd) {
                    do_gc();
                    RA = root_[A]; RB = root_[B];
                    lenA = R_LEN(RA); lenB = R_LEN(RB);
                }
                int offA = R_OFF(RA), capA = R_CAP(RA);
                int offB = R_OFF(RB), capB = R_CAP(RB);
                int offS, lenS, offL, lenL, capL;
                if (lenA <= lenB) { offS = offA; lenS = lenA; offL = offB; lenL = lenB; capL = capB; }
                else              { offS = offB; lenS = lenB; offL = offA; lenL = lenA; capL = capA; }
                int same = 0, dOff, dLen, dCap;

                if (lenS + lenL <= 64) {
                    u32 eL = (lane < lenL) ? pool_[offL + lane] : 0u;
                    u32 eS = (lane < lenS) ? pool_[offS + lane] : 0u;
                    dLen = lenL;
                    for (int t2 = 0; t2 < lenS; ++t2) {
                        u32 xs = (u32)rdl((int)eS, t2);
                        bool match = (lane < lenL) && ((eL >> 16) == (xs >> 16));
                        u64 mb = __ballot(match);
                        if (mb) {
                            int ml = __ffsll(mb) - 1;
                            same += (int)(xs & 0xFFFF) * ((int)rdl((int)eL, ml) & 0xFFFF);
                            if (match) eL += (xs & 0xFFFF);
                        } else {
                            if (lane == dLen) eL = xs;
                            dLen++;
                        }
                    }
                    if (dLen <= capL) { dOff = offL; dCap = capL; }
                    else { dOff = (int)bump; dCap = (dLen + 3) & ~3; bump += (u32)dCap; }
                    if (lane < dLen) pool_[dOff + lane] = eL;
                } else {
                    dOff = (int)bump;
                    dCap = (lenL + lenS + 4) & ~3; bump += (u32)dCap;
                    for (int j = lane; j < lenS; j += 64) {
                        u32 es = pool_[offS + j];
                        H_[es >> 16] = (short)(es & 0xFFFF);
                    }
                    __builtin_amdgcn_wave_barrier();
                    int sp = 0;
                    for (int j = lane; j < lenL; j += 64) {
                        u32 el = pool_[offL + j];
                        int h = (int)H_[el >> 16];
                        sp += h * (int)(el & 0xFFFF);
                        pool_[dOff + j] = el + (u32)h;
                        if (h) H_[el >> 16] = 0;
                    }
                    same = wredi(sp);
                    __builtin_amdgcn_wave_barrier();
                    int baseU = 0;
                    for (int j0 = 0; j0 < lenS; j0 += 64) {
                        int j = j0 + lane;
                        bool un = false; u32 es = 0;
                        if (j < lenS) { es = pool_[offS + j]; un = (H_[es >> 16] != 0); }
                        u64 ub = __ballot(un);
                        if (un) {
                            int pos = __popcll(ub & ltm);
                            pool_[dOff + lenL + baseU + pos] = es;
                            H_[es >> 16] = 0;
                        }
                        baseU += __popcll(ub);
                    }
                    dLen = lenL + baseU;
                }
                if (lane == 0) {
                    Qw_[qn] = (float)(ph ? same : (sLa * sLb - same));
                    Q_[qn]  = (u32)e;
                    root_[A] = packRoot(sLa + sLb, dOff, dLen, dCap);
                    root_[B] = 0;
                }
                qn++;
            } else {
                w_ = lA ? ca : (lB ? cb : (ca < cb ? ca : cb));
                l_ = (w_ == ca) ? cb : ca;
            }
            RELAB(l_, w_);
        }
    }

    // ---- epilogue per wave: sums over the qn recorded (merge) edges only ----
    float s_loc = 0.0f;
    for (int q = lane; q < qn; q += 64) s_loc += Qw_[q];
    const float sn = wredf(s_loc);

    const float scale = ph ? lrp_p[0] : lr_p[0];
    float acc = 0.0f;
    for (int q = lane; q < qn; q += 64) {
        float wv2 = Qw_[q];
        if (wv2 == 0.0f) continue;
        if (sn > 0.0f) wv2 /= sn;
        int me = (int)Q_[q];
        int g = gtcL[me];
        bool zero = ph ? (g < 20) : (g >= 10);
        if (zero) continue;
        u32 ab = eab[me];
        float pa = predL[ab & 0xFFFF], pb = predL[ab >> 16];
        float fa2, fb2;
        if (ph == 0) { fa2 = pa * pa; fb2 = pb * pb; }
        else { float qa = 20.0f - pa, qb = 20.0f - pb; fa2 = qa * qa; fb2 = qb * qb; }
        acc += scale * wv2 * (fa2 + fb2);
    }
    acc = wredf(acc);
    if (lane == 0) atomicAdd(out, acc);
}

__global__ void zero_out_kernel(float* o)
{
    if (threadIdx.x == 0 && blockIdx.x == 0) o[0] = 0.0f;
}

extern "C" void kernel_launch(void* const* d_in, const int* in_sizes, int n_in,
                              void* d_out, int out_size, void* d_ws, size_t ws_size,
                              hipStream_t stream)
{
    const float* pred   = (const float*)d_in[0];
    const float* target = (const float*)d_in[1];
    const float* lr     = (const float*)d_in[2];
    const float* lrp    = (const float*)d_in[3];
    float* out = (float*)d_out;

    zero_out_kernel<<<1, 64, 0, stream>>>(out);
    malis_kernel<<<128, 128, 0, stream>>>(pred, target, lr, lrp, out);
}

// Round 12
// 520.251 us; speedup vs baseline: 1.3602x; 1.3602x over previous
//
#include <hip/hip_runtime.h>
#include <cstdint>

#define NPIX  1024
#define NH    992
#define NEDGE 1984
#define NSORT 2048
#define NGRP  31
#define HFS   4300
#define POOLN (NPIX + 2*HFS)   // 9624 u32 entries per phase

typedef unsigned long long u64;
typedef unsigned int u32;

// root_ pack (labeled live sets only; 0 == dead/unlabeled):
// sL[0,11) | off[11,25) | len[25,36) | cap[36,47)
static __device__ __forceinline__ u64 packRoot(int sL,int off,int len,int cap){
    return (u64)(u32)(sL & 0x7FF) | ((u64)(u32)(off & 0x3FFF) << 11) |
           ((u64)(u32)(len & 0x7FF) << 25) | ((u64)(u32)(cap & 0x7FF) << 36);
}
#define R_SL(R)  ((int)((R) & 0x7FF))
#define R_OFF(R) ((int)(((R)>>11) & 0x3FFF))
#define R_LEN(R) ((int)(((R)>>25) & 0x7FF))
#define R_CAP(R) ((int)(((R)>>36) & 0x7FF))

static __device__ __forceinline__ int rdl(int v, int l){ return __builtin_amdgcn_readlane(v, l); }

static __device__ __forceinline__ u64 sxor64(u64 v, int m){
    u32 lo = (u32)__shfl_xor((int)(v & 0xFFFFFFFFull), m, 64);
    u32 hi = (u32)__shfl_xor((int)(v >> 32), m, 64);
    return ((u64)hi << 32) | lo;
}

// in-register compare-exchange: x at lower global index
#define CE(x, y, up) { u64 _a=(x), _b=(y); bool _lt=(_a<_b); \
    u64 _mn=_lt?_a:_b, _mx=_lt?_b:_a; (x)=(up)?_mn:_mx; (y)=(up)?_mx:_mn; }
// cross-lane compare-exchange via shfl_xor
#define CEX(x, xm, keepmin) { u64 _p=sxor64((x),(xm)); bool _lt=((x)<_p); \
    u64 _mn=_lt?(x):_p, _mx=_lt?_p:(x); (x)=(keepmin)?_mn:_mx; }

static __device__ __forceinline__ int wredi(int v){
    #pragma unroll
    for (int o = 32; o > 0; o >>= 1) v += __shfl_xor(v, o, 64);
    return v;
}
static __device__ __forceinline__ float wredf(float v){
    #pragma unroll
    for (int o = 32; o > 0; o >>= 1) v += __shfl_xor(v, o, 64);
    return v;
}

__global__ __launch_bounds__(128) void malis_kernel(
    const float* __restrict__ pred,
    const float* __restrict__ target,
    const float* __restrict__ lr_p,
    const float* __restrict__ lrp_p,
    float* __restrict__ out)
{
    const int tid  = threadIdx.x;
    const int lane = tid & 63;
    const int wv   = tid >> 6;        // wave 0: negative pass, wave 1: positive pass
    const int bid  = blockIdx.x;
    const int bb   = bid >> 6;
    const int win  = bid & 63;
    const int wy   = win >> 3, wx = win & 7;
    const int base = bb * 65536 + (wy * 32) * 256 + wx * 32;

    // ---- LDS (~156 KB; 1 block/CU) ----
    __shared__ __align__(16) u32 Ks[2][NSORT]; // 16384 rank->edge, then F list (in place)
    __shared__ u64   root[2][NPIX];         // 16384 labeled-set metadata
    __shared__ float predL[NPIX];           // 4096
    __shared__ u32   eab[NEDGE];            // 7936  a | b<<16
    __shared__ u32   poolS[2][POOLN];       // 76992 pool; [NPIX,NPIX+1024) = m_ scratch
    __shared__ u32   Q[2][NPIX];            // 8192  event records {e,argA,argB}
    __shared__ float Qw[2][NPIX];           // 8192  weights (minE claim array in Boruvka)
    __shared__ unsigned short rnk[2][NEDGE];// 7936  edge -> rank
    __shared__ short seg[NPIX];             // 2048
    __shared__ short comp[2][NPIX];         // 4096  flat comp ids / cluster UF
    __shared__ short H[2][NPIX + 1];        // 4100  (slow-path histogram only)
    __shared__ u32   fb[2][64];             // 512   forest-edge bitmap
    __shared__ unsigned char tgtL[NPIX];    // 1024
    __shared__ unsigned char gtcL[NEDGE];   // 1984
    __shared__ int   flags[2];

    // early scratch overlaid on poolS (dead until UF init)
    unsigned char* mA    = (unsigned char*)poolS;
    unsigned char* mB    = mA + NPIX;
    short*         labId = (short*)(mA + 2 * NPIX);

    // ---- load window ----
    for (int i = tid; i < NPIX; i += 128) {
        int r = i >> 5, c = i & 31;
        float pv = pred[base + r * 256 + c];
        float tv = target[base + r * 256 + c];
        predL[i] = pv;
        tgtL[i]  = (unsigned char)tv;
        mA[i]    = (tv == 0.0f) ? 1 : 0;
    }
    if (tid == 0) flags[1] = 0;
    __syncthreads();

    // ---- dilate 5x (4-neighborhood) ----
    unsigned char* srcm = mA;
    unsigned char* dstm = mB;
    for (int it = 0; it < 5; ++it) {
        for (int i = tid; i < NPIX; i += 128) {
            int r = i >> 5, c = i & 31;
            unsigned char v = srcm[i];
            if (r > 0)  v |= srcm[i - 32];
            if (r < 31) v |= srcm[i + 32];
            if (c > 0)  v |= srcm[i - 1];
            if (c < 31) v |= srcm[i + 1];
            dstm[i] = v;
        }
        __syncthreads();
        unsigned char* t2 = srcm; srcm = dstm; dstm = t2;
    }

    // ---- CCL (8-conn) on fg = !dilated ----
    for (int i = tid; i < NPIX; i += 128)
        seg[i] = srcm[i] ? (short)-1 : (short)i;
    __syncthreads();

    for (;;) {
        if (tid == 0) flags[0] = 0;
        __syncthreads();
        bool any = false;
        for (int i = tid; i < NPIX; i += 128) {
            int cur = seg[i];
            if (cur < 0) continue;
            int r = i >> 5, c = i & 31;
            int m = cur;
            if (r > 0) {
                if (c > 0)  { int t = seg[i - 33]; if (t >= 0 && t < m) m = t; }
                { int t = seg[i - 32]; if (t >= 0 && t < m) m = t; }
                if (c < 31) { int t = seg[i - 31]; if (t >= 0 && t < m) m = t; }
            }
            if (c > 0)  { int t = seg[i - 1]; if (t >= 0 && t < m) m = t; }
            if (c < 31) { int t = seg[i + 1]; if (t >= 0 && t < m) m = t; }
            if (r < 31) {
                if (c > 0)  { int t = seg[i + 31]; if (t >= 0 && t < m) m = t; }
                { int t = seg[i + 32]; if (t >= 0 && t < m) m = t; }
                if (c < 31) { int t = seg[i + 33]; if (t >= 0 && t < m) m = t; }
            }
            #pragma unroll
            for (int t2 = 0; t2 < 6; ++t2) {
                int s2 = seg[m];
                if (s2 >= 0 && s2 < m) m = s2; else break;
            }
            if (m < cur) { seg[i] = (short)m; any = true; }
        }
        if (any) flags[0] = 1;
        __syncthreads();
        if (flags[0] == 0) break;
        __syncthreads();
    }

    // compact label ids: seg -> 0 (bg) or 1..K
    for (int i = tid; i < NPIX; i += 128)
        if (seg[i] == (short)i) labId[i] = (short)atomicAdd(&flags[1], 1);
    __syncthreads();
    for (int i = tid; i < NPIX; i += 128) {
        short s2 = seg[i];
        seg[i] = (s2 < 0) ? (short)0 : (short)(labId[s2] + 1);
    }

    // ---- edges (reference order: 992 horizontal then 992 vertical) ----
    for (int e = tid; e < NEDGE; e += 128) {
        int a, b2;
        if (e < NH) { int r = e / 31, c = e - r * 31; a = r * 32 + c; b2 = a + 1; }
        else        { int q = e - NH; int r = q >> 5, c = q & 31; a = r * 32 + c; b2 = a + 32; }
        eab[e]   = (u32)a | ((u32)b2 << 16);
        gtcL[e]  = (unsigned char)(tgtL[a] + tgtL[b2]);
    }
    __syncthreads();
    // ======== no block barriers below this line: waves fully decoupled ========

    const int ph = wv;                 // 0 = neg, 1 = pos
    u32*   Ks_   = Ks[ph];
    short* comp_ = comp[ph];
    u64*   root_ = root[ph];
    u32*   pool_ = poolS[ph];
    short* H_    = H[ph];
    u32*   Q_    = Q[ph];
    float* Qw_   = Qw[ph];
    u32*   minE_ = (u32*)Qw[ph];       // Boruvka min-edge per comp (Qw dead till replay)
    u32*   m_    = pool_ + NPIX;       // min-bottleneck packed (m<<16|arg); dead at replay
    unsigned short* rnk_ = rnk[ph];
    u32*   fb_   = fb[ph];

    // ---- register-resident bitonic sort of 2048 u64 keys ----
    // key = (~bits(cost))<<32 | e ; ascending == (cost desc, idx asc) == ref order
    u64 sk[32];
    #pragma unroll
    for (int r = 0; r < 32; ++r) {
        int e = lane * 32 + r;
        u64 kv = ~0ULL;                       // padding sorts to tail
        if (e < NEDGE) {
            u32 ab = eab[e];
            float cv = predL[ab & 0xFFFF] + predL[ab >> 16];
            int g = gtcL[e];
            if (ph == 0) { if (g > 20) cv = 20.0f; }
            else         { if (g < 10) cv = 0.0f; }
            kv = (((u64)(~__float_as_uint(cv))) << 32) | (u32)e;  // costs >= 0: monotone bits
        }
        sk[r] = kv;
    }
    #pragma unroll
    for (int kk2 = 2; kk2 <= 32; kk2 <<= 1) {
        #pragma unroll
        for (int j = kk2 >> 1; j > 0; j >>= 1) {
            #pragma unroll
            for (int r = 0; r < 32; ++r) {
                if ((r & j) == 0) {
                    bool up = (kk2 == 32) ? ((lane & 1) == 0) : ((r & kk2) == 0);
                    CE(sk[r], sk[r | j], up);
                }
            }
        }
    }
    #pragma unroll
    for (int kk2 = 64; kk2 <= 2048; kk2 <<= 1) {
        const bool up = ((lane & (kk2 >> 5)) == 0);
        #pragma unroll
        for (int j = kk2 >> 1; j >= 32; j >>= 1) {
            const int xm = j >> 5;
            const bool keepmin = (((lane & xm) == 0) == up);
            #pragma unroll
            for (int r = 0; r < 32; ++r) { CEX(sk[r], xm, keepmin); }
        }
        #pragma unroll
        for (int j = 16; j > 0; j >>= 1) {
            #pragma unroll
            for (int r = 0; r < 32; ++r) {
                if ((r & j) == 0) { CE(sk[r], sk[r | j], up); }
            }
        }
    }
    // writeback rank->edge AND scatter edge->rank
    #pragma unroll
    for (int r = 0; r < 32; ++r) {
        u32 lo = (u32)sk[r];
        Ks_[lane * 32 + r] = lo;
        if (lo < NEDGE) rnk_[lo] = (unsigned short)(lane * 32 + r);
    }

    // ---- init: comp flat, labeled pool sets, m_, fb ----
    for (int k = 0; k < 16; ++k) {
        int i = k * 64 + lane;
        comp_[i] = (short)i;
        short s2 = seg[i];
        if (s2) {
            root_[i] = packRoot(1, i, 1, 1);
            pool_[i] = ((u32)(unsigned short)s2 << 16) | 1u;
            m_[i]    = (u32)i;                 // m=0, arg=i
        } else {
            root_[i] = 0;
            m_[i]    = 0xFFFFFFFFu;            // m=INF
        }
        H_[i] = 0;
    }
    if (lane == 0) { H_[NPIX] = 0; fb_[62] = 0; fb_[63] = 0; }
    if (lane < 62) fb_[lane] = 0;
    __builtin_amdgcn_wave_barrier();

    // ---- Boruvka on flat comp[]: greedy forest F (= Kruskal merge set) ----
    {
        u32 deadmask = 0;
        for (int round = 0; round < 12; ++round) {
            for (int k = 0; k < 16; ++k) minE_[k * 64 + lane] = ~0u;
            __builtin_amdgcn_wave_barrier();
            bool anyAlive = false;
            #pragma unroll
            for (int j = 0; j < NGRP; ++j) {           // independent iters: pipelines
                if ((deadmask >> j) & 1) continue;
                int e = j * 64 + lane;
                u32 ab = eab[e];
                int ca = comp_[ab & 0xFFFF];
                int cb = comp_[ab >> 16];
                if (ca == cb) { deadmask |= 1u << j; continue; }
                anyAlive = true;
                u32 v = ((u32)rnk_[e] << 11) | (u32)e;
                atomicMin(&minE_[ca], v);
                atomicMin(&minE_[cb], v);
            }
            u64 alv = __ballot(anyAlive);
            __builtin_amdgcn_wave_barrier();
            if (!alv) break;
            // two-pass hooking (pass1: stable reads into regs; pass2: writes)
            int tgt[16], tge[16];
            for (int k = 0; k < 16; ++k) {
                int i = k * 64 + lane;
                tgt[k] = -1;
                if (comp_[i] != (short)i) continue;
                u32 v = minE_[i];
                if (v == ~0u) continue;
                int e = (int)(v & 0x7FF);
                u32 ab = eab[e];
                int ca = comp_[ab & 0xFFFF];
                int cb = comp_[ab >> 16];
                int o = (ca == i) ? cb : ca;
                if (minE_[o] == v && i < o) continue;   // 2-cycle: o hooks to i
                tgt[k] = o; tge[k] = e;
            }
            __builtin_amdgcn_wave_barrier();
            for (int k = 0; k < 16; ++k) {
                if (tgt[k] >= 0) {
                    comp_[k * 64 + lane] = (short)tgt[k];
                    atomicOr(&fb_[tge[k] >> 5], 1u << (tge[k] & 31));
                }
            }
            __builtin_amdgcn_wave_barrier();
            // recompress to flat (pointer jumping)
            for (int it2 = 0; it2 < 12; ++it2) {
                bool ch = false;
                for (int k = 0; k < 16; ++k) {
                    int p = k * 64 + lane;
                    int q1 = comp_[p];
                    int q2 = comp_[q1];
                    if (q2 != q1) { comp_[p] = (short)q2; ch = true; }
                }
                u64 cb2 = __ballot(ch);
                __builtin_amdgcn_wave_barrier();
                if (!cb2) break;
            }
        }
    }

    // ---- compact forest edges (rank order) in place into Ks_[0..nF) ----
    int nF = 0;
    const u64 ltm = (1ull << lane) - 1;
    for (int g2 = 0; g2 < NGRP; ++g2) {
        u32 e = Ks_[g2 * 64 + lane];
        bool isf = (fb_[e >> 5] >> (e & 31)) & 1u;
        u64 m = __ballot(isf);
        __builtin_amdgcn_wave_barrier();
        int pos = nF + (int)__popcll(m & ltm);
        if (isf) Ks_[pos] = e;
        nF += (int)__popcll(m);
    }
    __builtin_amdgcn_wave_barrier();

    // ---- min-bottleneck relaxation on F (minimax preserved by MSF) ----
    // m_(x) = packed (minmax-rank to nearest labeled)<<16 | arg pixel.
    // Monotone atomicMin; ballot fixpoint. Races benign (re-applied next pass).
    u32 fe[16];
    for (int k = 0; k < 16; ++k) {
        int idx = k * 64 + lane;
        u32 p = ~0u;
        if (idx < nF) {
            int e = (int)Ks_[idx];
            u32 ab = eab[e];
            p = (ab & 0x3FF) | (((ab >> 16) & 0x3FF) << 10) | ((u32)rnk_[e] << 20);
        }
        fe[k] = p;
    }
    for (;;) {
        bool ch = false;
        #pragma unroll
        for (int k = 0; k < 16; ++k) {
            u32 p = fe[k];
            if (p == ~0u) continue;
            int a = (int)(p & 0x3FF), b = (int)((p >> 10) & 0x3FF);
            u32 r = p >> 20;
            u32 pa = m_[a], pb = m_[b];
            u32 ma = pa >> 16, mb = pb >> 16;
            if (ma != 0xFFFFu) {
                u32 na = ma > r ? ma : r;
                u32 cand = (na << 16) | (pa & 0xFFFF);
                if (cand < pb) { atomicMin(&m_[b], cand); ch = true; }
            }
            if (mb != 0xFFFFu) {
                u32 nb = mb > r ? mb : r;
                u32 cand = (nb << 16) | (pb & 0xFFFF);
                if (cand < pa) { atomicMin(&m_[a], cand); ch = true; }
            }
        }
        u64 cb3 = __ballot(ch);
        __builtin_amdgcn_wave_barrier();
        if (!cb3) break;
    }

    // ---- extract weighted events in rank order: F edge e=(a,b,r) is an event
    // iff m(a)<r && m(b)<r (both sides of F_{<r} contain labels; args on sides)
    int qn = 0;
    for (int b0 = 0; b0 < nF; b0 += 64) {
        int idx = b0 + lane;
        bool ev = false; u32 rec = 0;
        if (idx < nF) {
            int e = (int)Ks_[idx];
            u32 ab = eab[e];
            int a = (int)(ab & 0xFFFF), b = (int)(ab >> 16);
            u32 r = rnk_[e];
            u32 pa = m_[a], pb = m_[b];
            ev = ((pa >> 16) < r) && ((pb >> 16) < r);
            rec = (u32)e | ((pa & 0x3FF) << 11) | ((pb & 0x3FF) << 21);
        }
        u64 mk = __ballot(ev);
        if (ev) Q_[qn + __popcll(mk & ltm)] = rec;
        qn += (int)__popcll(mk);
    }
    __builtin_amdgcn_wave_barrier();

    // ---- replay the ~89 events in rank order (cluster UF over arg pixels) ----
    for (int k = 0; k < 16; ++k) comp_[k * 64 + lane] = (short)(k * 64 + lane);
    __builtin_amdgcn_wave_barrier();

    u32 bump = NPIX + NPIX;            // pool allocs start after m_ scratch
    u32 halfEnd = NPIX + HFS;
    int curHalf = 0;

    auto do_gc = [&]() {               // ping-pong compaction
        u32 tgt2 = (curHalf == 0) ? (u32)(NPIX + HFS) : (u32)NPIX;
        u32 nb = tgt2;
        for (int c = 0; c < 16; ++c) {
            int i0 = c * 64 + lane;
            bool live = (root_[i0] != 0);
            u64 rbm = __ballot(live);
            while (rbm) {
                int j = __ffsll(rbm) - 1; rbm &= rbm - 1;
                int r = c * 64 + j;
                u64 R = root_[r];
                int len = R_LEN(R);
                int off = R_OFF(R);
                for (int t = lane; t < len; t += 64) {
                    u32 v2 = pool_[off + t];
                    pool_[nb + t] = v2;
                }
                __builtin_amdgcn_wave_barrier();
                if (lane == 0) root_[r] = packRoot(R_SL(R), (int)nb, len, len);
                nb += (u32)len;
            }
        }
        bump = nb;
        halfEnd = tgt2 + HFS;
        curHalf ^= 1;
    };

    int lastW = -1; u64 lastPack = 0;
    for (int q = 0; q < qn; ++q) {
        u32 rec = Q_[q];
        int aA = (int)((rec >> 11) & 0x3FF);
        int aB = (int)((rec >> 21) & 0x3FF);
        int ca = aA; for (;;) { int p = comp_[ca]; if (p == ca) break; ca = p; }
        int cb = aB; for (;;) { int p = comp_[cb]; if (p == cb) break; cb = p; }
        if (lane == 0) { comp_[aA] = (short)ca; comp_[aB] = (short)cb; }
        int A = ca < cb ? ca : cb;
        int B = ca < cb ? cb : ca;
        u64 RA = (A == lastW) ? lastPack : root_[A];
        u64 RB = (B == lastW) ? lastPack : root_[B];
        int sLa = R_SL(RA), sLb = R_SL(RB);
        int lenA = R_LEN(RA), lenB = R_LEN(RB);
        if (bump + (u32)(lenA + lenB + 8) > halfEnd) {
            do_gc();
            lastW = -1;
            RA = root_[A]; RB = root_[B];
            lenA = R_LEN(RA); lenB = R_LEN(RB);
        }
        int offA = R_OFF(RA), capA = R_CAP(RA);
        int offB = R_OFF(RB), capB = R_CAP(RB);
        int offS, lenS, offL, lenL, capL;
        if (lenA <= lenB) { offS = offA; lenS = lenA; offL = offB; lenL = lenB; capL = capB; }
        else              { offS = offB; lenS = lenB; offL = offA; lenL = lenA; capL = capA; }
        int same = 0, dOff, dLen, dCap;

        if (lenS + lenL <= 64) {
            // register path: lists live in lanes; match via readlane+ballot
            u32 eL = (lane < lenL) ? pool_[offL + lane] : 0u;
            u32 eS = (lane < lenS) ? pool_[offS + lane] : 0u;
            dLen = lenL;
            for (int t2 = 0; t2 < lenS; ++t2) {
                u32 xs = (u32)rdl((int)eS, t2);
                bool match = (lane < lenL) && ((eL >> 16) == (xs >> 16));
                u64 mb = __ballot(match);
                if (mb) {
                    int ml = __ffsll(mb) - 1;
                    same += (int)(xs & 0xFFFF) * ((int)rdl((int)eL, ml) & 0xFFFF);
                    if (match) eL += (xs & 0xFFFF);
                } else {
                    if (lane == dLen) eL = xs;
                    dLen++;
                }
            }
            if (dLen <= capL) { dOff = offL; dCap = capL; }
            else { dOff = (int)bump; dCap = (dLen + 3) & ~3; bump += (u32)dCap; }
            if (lane < dLen) pool_[dOff + lane] = eL;
        } else {
            // slow generic: stride loops + LDS histogram
            dOff = (int)bump;
            dCap = (lenL + lenS + 4) & ~3; bump += (u32)dCap;
            for (int j = lane; j < lenS; j += 64) {
                u32 es = pool_[offS + j];
                H_[es >> 16] = (short)(es & 0xFFFF);
            }
            __builtin_amdgcn_wave_barrier();
            int sp = 0;
            for (int j = lane; j < lenL; j += 64) {
                u32 el = pool_[offL + j];
                int h = (int)H_[el >> 16];
                sp += h * (int)(el & 0xFFFF);
                pool_[dOff + j] = el + (u32)h;
                if (h) H_[el >> 16] = 0;
            }
            same = wredi(sp);
            __builtin_amdgcn_wave_barrier();
            int baseU = 0;
            for (int j0 = 0; j0 < lenS; j0 += 64) {
                int j = j0 + lane;
                bool un = false; u32 es = 0;
                if (j < lenS) { es = pool_[offS + j]; un = (H_[es >> 16] != 0); }
                u64 ub = __ballot(un);
                if (un) {
                    int pos = __popcll(ub & ltm);
                    pool_[dOff + lenL + baseU + pos] = es;
                    H_[es >> 16] = 0;
                }
                baseU += __popcll(ub);
            }
            dLen = lenL + baseU;
        }
        u64 newPack = packRoot(sLa + sLb, dOff, dLen, dCap);
        if (lane == 0) {
            Qw_[q] = (float)(ph ? same : (sLa * sLb - same));
            root_[A] = newPack;
            root_[B] = 0;
            comp_[B] = (short)A;
        }
        lastW = A; lastPack = newPack;
        __builtin_amdgcn_wave_barrier();
    }

    // ---- epilogue per wave: sums over the qn recorded (event) edges only ----
    float s_loc = 0.0f;
    for (int q = lane; q < qn; q += 64) s_loc += Qw_[q];
    const float sn = wredf(s_loc);

    const float scale = ph ? lrp_p[0] : lr_p[0];
    float acc = 0.0f;
    for (int q = lane; q < qn; q += 64) {
        float wv2 = Qw_[q];
        if (wv2 == 0.0f) continue;
        if (sn > 0.0f) wv2 /= sn;
        int me = (int)(Q_[q] & 0x7FF);
        int g = gtcL[me];
        bool zero = ph ? (g < 20) : (g >= 10);
        if (zero) continue;
        u32 ab = eab[me];
        float pa = predL[ab & 0xFFFF], pb = predL[ab >> 16];
        float fa2, fb2;
        if (ph == 0) { fa2 = pa * pa; fb2 = pb * pb; }
        else { float qa = 20.0f - pa, qb = 20.0f - pb; fa2 = qa * qa; fb2 = qb * qb; }
        acc += scale * wv2 * (fa2 + fb2);
    }
    acc = wredf(acc);
    if (lane == 0) atomicAdd(out, acc);
}

__global__ void zero_out_kernel(float* o)
{
    if (threadIdx.x == 0 && blockIdx.x == 0) o[0] = 0.0f;
}

extern "C" void kernel_launch(void* const* d_in, const int* in_sizes, int n_in,
                              void* d_out, int out_size, void* d_ws, size_t ws_size,
                              hipStream_t stream)
{
    const float* pred   = (const float*)d_in[0];
    const float* target = (const float*)d_in[1];
    const float* lr     = (const float*)d_in[2];
    const float* lrp    = (const float*)d_in[3];
    float* out = (float*)d_out;

    zero_out_kernel<<<1, 64, 0, stream>>>(out);
    malis_kernel<<<128, 128, 0, stream>>>(pred, target, lr, lrp, out);
}

// Round 13
// 488.583 us; speedup vs baseline: 1.4483x; 1.0648x over previous
//
#include <hip/hip_runtime.h>
#include <cstdint>

#define NPIX  1024
#define NH    992
#define NEDGE 1984
#define NSORT 2048
#define NGRP  31
#define HFS   4300
#define POOLN (NPIX + 2*HFS)   // 9624 u32 entries per phase

typedef unsigned long long u64;
typedef unsigned int u32;

// root_ pack (labeled live sets only; 0 == dead/unlabeled):
// sL[0,11) | off[11,25) | len[25,36) | cap[36,47)
static __device__ __forceinline__ u64 packRoot(int sL,int off,int len,int cap){
    return (u64)(u32)(sL & 0x7FF) | ((u64)(u32)(off & 0x3FFF) << 11) |
           ((u64)(u32)(len & 0x7FF) << 25) | ((u64)(u32)(cap & 0x7FF) << 36);
}
#define R_SL(R)  ((int)((R) & 0x7FF))
#define R_OFF(R) ((int)(((R)>>11) & 0x3FFF))
#define R_LEN(R) ((int)(((R)>>25) & 0x7FF))
#define R_CAP(R) ((int)(((R)>>36) & 0x7FF))

static __device__ __forceinline__ int rdl(int v, int l){ return __builtin_amdgcn_readlane(v, l); }

static __device__ __forceinline__ u64 sxor64(u64 v, int m){
    u32 lo = (u32)__shfl_xor((int)(v & 0xFFFFFFFFull), m, 64);
    u32 hi = (u32)__shfl_xor((int)(v >> 32), m, 64);
    return ((u64)hi << 32) | lo;
}

// in-register compare-exchange: x at lower global index
#define CE(x, y, up) { u64 _a=(x), _b=(y); bool _lt=(_a<_b); \
    u64 _mn=_lt?_a:_b, _mx=_lt?_b:_a; (x)=(up)?_mn:_mx; (y)=(up)?_mx:_mn; }
// cross-lane compare-exchange via shfl_xor
#define CEX(x, xm, keepmin) { u64 _p=sxor64((x),(xm)); bool _lt=((x)<_p); \
    u64 _mn=_lt?(x):_p, _mx=_lt?_p:(x); (x)=(keepmin)?_mn:_mx; }

static __device__ __forceinline__ int wredi(int v){
    #pragma unroll
    for (int o = 32; o > 0; o >>= 1) v += __shfl_xor(v, o, 64);
    return v;
}
static __device__ __forceinline__ float wredf(float v){
    #pragma unroll
    for (int o = 32; o > 0; o >>= 1) v += __shfl_xor(v, o, 64);
    return v;
}

// union-find find with path compression on u32 parent array.
// Parent values only decrease (min-linking) => chains strictly decrease => terminates.
static __device__ __forceinline__ int findc(u32* P, int x){
    int r = x;
    for (;;) { int p = (int)P[r]; if (p == r) break; int g = (int)P[p]; P[r] = (u32)g; r = g; }
    return r;
}

__global__ __launch_bounds__(128) void malis_kernel(
    const float* __restrict__ pred,
    const float* __restrict__ target,
    const float* __restrict__ lr_p,
    const float* __restrict__ lrp_p,
    float* __restrict__ out)
{
    const int tid  = threadIdx.x;
    const int lane = tid & 63;
    const int wv   = tid >> 6;        // wave 0: negative pass, wave 1: positive pass
    const int bid  = blockIdx.x;
    const int bb   = bid >> 6;
    const int win  = bid & 63;
    const int wy   = win >> 3, wx = win & 7;
    const int base = bb * 65536 + (wy * 32) * 256 + wx * 32;

    // ---- LDS (~150 KB; 1 block/CU) ----
    __shared__ __align__(16) u32 Ks[2][NSORT]; // 16384 sorted edge indices
    __shared__ u64   root[2][NPIX];         // 16384 labeled-set metadata
    __shared__ float predL[NPIX];           // 4096
    __shared__ u32   eab[NEDGE];            // 7936  a | b<<16
    __shared__ u32   poolS[2][POOLN];       // 76992 label-count arrays {lab<<16|cnt}
    __shared__ u32   Q[2][NPIX];            // 8192  merge records {e,mn,mx}
    __shared__ float Qw[2][NPIX];           // 8192  weights (CCL parent scratch in prep)
    __shared__ short segP[2][NPIX];         // 4096  per-phase labels (root+1, bg=0)
    __shared__ short par[2][NPIX];          // 4096  drain union-find
    __shared__ short H[2][NPIX + 1];        // 4100  slow-path histogram
    __shared__ u32   fgw[2][32];            // 256   fg row bitmasks
    __shared__ unsigned char tgtL[NPIX];    // 1024
    __shared__ unsigned char gtcL[NEDGE];   // 1984

    // ---- block: load window ----
    for (int i = tid; i < NPIX; i += 128) {
        int r = i >> 5, c = i & 31;
        predL[i] = pred[base + r * 256 + c];
        tgtL[i]  = (unsigned char)target[base + r * 256 + c];
    }
    __syncthreads();

    // ---- block: edges (reference order: 992 horizontal then 992 vertical) ----
    for (int e = tid; e < NEDGE; e += 128) {
        int a, b2;
        if (e < NH) { int r = e / 31, c = e - r * 31; a = r * 32 + c; b2 = a + 1; }
        else        { int q = e - NH; int r = q >> 5, c = q & 31; a = r * 32 + c; b2 = a + 32; }
        eab[e]  = (u32)a | ((u32)b2 << 16);
        gtcL[e] = (unsigned char)(tgtL[a] + tgtL[b2]);
    }
    __syncthreads();
    // ======== no block barriers below this line: waves fully decoupled ========

    const int ph = wv;                 // 0 = neg, 1 = pos
    u32*   Ks_   = Ks[ph];
    short* par_  = par[ph];
    u64*   root_ = root[ph];
    u32*   pool_ = poolS[ph];
    short* H_    = H[ph];
    u32*   Q_    = Q[ph];
    float* Qw_   = Qw[ph];
    short* seg_  = segP[ph];
    u32*   fg_   = fgw[ph];
    u32*   P     = (u32*)Qw[ph];       // CCL parent scratch (Qw dead until replay)

    // ---- per-wave: zero-mask rows via ballot; dilate 5x in registers ----
    for (int k = 0; k < 16; ++k) {
        bool z = (tgtL[k * 64 + lane] == 0);
        u64 bal = __ballot(z);
        if (lane == 0) { fg_[2 * k] = (u32)bal; fg_[2 * k + 1] = (u32)(bal >> 32); }
    }
    __builtin_amdgcn_wave_barrier();
    {
        u32 row = (lane < 32) ? fg_[lane] : 0u;
        #pragma unroll
        for (int it = 0; it < 5; ++it) {
            u32 up = (u32)__shfl((int)row, lane - 1, 64); if (lane == 0)  up = 0;
            u32 dn = (u32)__shfl((int)row, lane + 1, 64); if (lane >= 31) dn = 0;
            row = row | (row << 1) | (row >> 1) | up | dn;
        }
        if (lane < 32) fg_[lane] = ~row;   // fg = NOT dilated
    }
    __builtin_amdgcn_wave_barrier();

    // ---- per-wave CCL (8-conn) via atomicMin union-find (Komura-style) ----
    for (int k = 0; k < 16; ++k) P[k * 64 + lane] = (u32)(k * 64 + lane);
    __builtin_amdgcn_wave_barrier();
    for (int iter = 0; iter < 16; ++iter) {
        bool changed = false;
        for (int k = 0; k < 16; ++k) {
            int i = k * 64 + lane;
            int rr = i >> 5, cc = i & 31;
            if (!((fg_[rr] >> cc) & 1u)) continue;
            int r = findc(P, i);
            u32 wm = (rr > 0)  ? fg_[rr - 1] : 0u;
            u32 w0 = fg_[rr];
            u32 wp = (rr < 31) ? fg_[rr + 1] : 0u;
            #pragma unroll
            for (int t = 0; t < 8; ++t) {
                static const int dr[8] = {-1,-1,-1, 0,0, 1,1,1};
                static const int dc[8] = {-1, 0, 1,-1,1,-1,0,1};
                int nr = rr + dr[t], nc = cc + dc[t];
                if ((unsigned)nr >= 32u || (unsigned)nc >= 32u) continue;
                u32 wrow = (dr[t] < 0) ? wm : ((dr[t] > 0) ? wp : w0);
                if (!((wrow >> nc) & 1u)) continue;
                int rj = findc(P, nr * 32 + nc);
                if (rj == r) continue;
                int lo = rj < r ? rj : r;
                int hi = rj < r ? r : rj;
                u32 old = atomicMin(&P[hi], (u32)lo);
                if (old > (u32)lo) changed = true;
                r = lo;
            }
        }
        u64 cb = __ballot(changed);
        __builtin_amdgcn_wave_barrier();
        if (!cb) break;
    }
    // finalize labels: root pixel index + 1 (deterministic; no compaction needed)
    for (int k = 0; k < 16; ++k) {
        int i = k * 64 + lane;
        int rr = i >> 5, cc = i & 31;
        seg_[i] = ((fg_[rr] >> cc) & 1u) ? (short)(findc(P, i) + 1) : (short)0;
    }
    __builtin_amdgcn_wave_barrier();

    // ---- register-resident bitonic sort of 2048 u64 keys ----
    // key = (~bits(cost))<<32 | e ; ascending == (cost desc, idx asc) == ref order
    u64 sk[32];
    #pragma unroll
    for (int r = 0; r < 32; ++r) {
        int e = lane * 32 + r;
        u64 kv = ~0ULL;                       // padding sorts to tail
        if (e < NEDGE) {
            u32 ab = eab[e];
            float cv = predL[ab & 0xFFFF] + predL[ab >> 16];
            int g = gtcL[e];
            if (ph == 0) { if (g > 20) cv = 20.0f; }
            else         { if (g < 10) cv = 0.0f; }
            kv = (((u64)(~__float_as_uint(cv))) << 32) | (u32)e;  // costs >= 0: monotone bits
        }
        sk[r] = kv;
    }
    #pragma unroll
    for (int kk2 = 2; kk2 <= 32; kk2 <<= 1) {
        #pragma unroll
        for (int j = kk2 >> 1; j > 0; j >>= 1) {
            #pragma unroll
            for (int r = 0; r < 32; ++r) {
                if ((r & j) == 0) {
                    bool up = (kk2 == 32) ? ((lane & 1) == 0) : ((r & kk2) == 0);
                    CE(sk[r], sk[r | j], up);
                }
            }
        }
    }
    #pragma unroll
    for (int kk2 = 64; kk2 <= 2048; kk2 <<= 1) {
        const bool up = ((lane & (kk2 >> 5)) == 0);
        #pragma unroll
        for (int j = kk2 >> 1; j >= 32; j >>= 1) {
            const int xm = j >> 5;
            const bool keepmin = (((lane & xm) == 0) == up);
            #pragma unroll
            for (int r = 0; r < 32; ++r) { CEX(sk[r], xm, keepmin); }
        }
        #pragma unroll
        for (int j = 16; j > 0; j >>= 1) {
            #pragma unroll
            for (int r = 0; r < 32; ++r) {
                if ((r & j) == 0) { CE(sk[r], sk[r | j], up); }
            }
        }
    }
    #pragma unroll
    for (int r = 0; r < 32; r += 4) {
        uint4 v4;
        v4.x = (u32)sk[r]; v4.y = (u32)sk[r+1]; v4.z = (u32)sk[r+2]; v4.w = (u32)sk[r+3];
        *(uint4*)&Ks_[lane * 32 + r] = v4;
    }

    // ---- union-find init; labeled pixel i owns pool slot i = {seg_[i], cnt 1} ----
    // Invariant (labeled-wins unions): comp labeled <=> seg_[root] != 0; labeled
    // sets change only at weighted merges (deferred to replay).
    for (int i = lane; i < NPIX; i += 64) {
        par_[i] = (short)i;
        short s2 = seg_[i];
        if (s2) {
            root_[i] = packRoot(1, i, 1, 1);
            pool_[i] = ((u32)(unsigned short)s2 << 16) | 1u;
        } else {
            root_[i] = 0;                     // 0 == not a live labeled set
        }
        H_[i] = 0;
    }
    if (lane == 0) H_[NPIX] = 0;
    __builtin_amdgcn_wave_barrier();

    // ---- Kruskal drain (R6 structure): tiny ballot loop, merges deferred ----
    int qn = 0;
    for (int g2 = 0; g2 < NGRP; ++g2) {
        int myE = (int)Ks_[g2 * 64 + lane];
        u32 ab = eab[myE];
        int ra = (int)(ab & 0xFFFF);
        int rb = (int)(ab >> 16);
        // interleaved dual find with path-halving (benign races)
        for (;;) {
            int pa = par_[ra], pb = par_[rb];
            bool fa = (pa != ra), fb = (pb != rb);
            if (!fa && !fb) break;
            int ga = par_[pa], gb = par_[pb];
            if (fa) { par_[ra] = (short)ga; ra = ga; }
            if (fb) { par_[rb] = (short)gb; rb = gb; }
        }
        u32 laA = (seg_[ra] != 0) ? 1u : 0u;
        u32 laB = (seg_[rb] != 0) ? 1u : 0u;
        bool alive = (ra != rb);
        u32 packed = (u32)ra | ((u32)rb << 10) | (laA << 20) | (laB << 21);
        int myLoser = -1, myWinner = 0;
        __builtin_amdgcn_wave_barrier();

        for (;;) {
            u64 bal = __ballot(alive);
            if (!bal) break;
            int srcl = __ffsll(bal) - 1;            // lowest lane == sorted order
            u32 v = (u32)rdl((int)packed, srcl);
            int mra = (int)(v & 0x3FF);
            int mrb = (int)((v >> 10) & 0x3FF);
            u32 lA = (v >> 20) & 1u, lB = (v >> 21) & 1u;
            int mn = mra < mrb ? mra : mrb;
            int mx = mra < mrb ? mrb : mra;
            int winner = (lA & ~lB) ? mra : ((lB & ~lA) ? mrb : mn);
            int loser  = (lA & ~lB) ? mrb : ((lB & ~lA) ? mra : mx);
            u32 labWin = lA | lB;
            if (lA & lB) {                          // weighted: record, defer sets
                if (lane == srcl) Q_[qn] = (u32)myE | ((u32)mn << 11) | ((u32)mx << 21);
                qn++;
            }
            if (lane == srcl) { myLoser = loser; myWinner = winner; }
            if (ra == loser) { ra = winner; laA = labWin; }
            if (rb == loser) { rb = winner; laB = labWin; }
            alive = alive && (ra != rb);            // srcl + collisions die here
            packed = (u32)ra | ((u32)rb << 10) | (laA << 20) | (laB << 21);
        }
        // batched union writes for next group's finds (each loser unique)
        if (myLoser >= 0) par_[myLoser] = (short)myWinner;
        __builtin_amdgcn_wave_barrier();
    }

    // ---- replay: ~89 weighted merges in recorded order (exact roots) ----
    u32 bump = NPIX;
    u32 halfEnd = NPIX + HFS;
    int curHalf = 0;
    const u64 ltm = (1ull << lane) - 1;

    auto do_gc = [&]() {           // ping-pong compaction; live entries <= 1024 < HFS
        u32 tgt = (curHalf == 0) ? (u32)(NPIX + HFS) : (u32)NPIX;
        u32 nb = tgt;
        for (int c = 0; c < 16; ++c) {
            int i0 = c * 64 + lane;
            bool live = (root_[i0] != 0);
            u64 rbm = __ballot(live);
            while (rbm) {
                int j = __ffsll(rbm) - 1; rbm &= rbm - 1;
                int r = c * 64 + j;
                u64 R = root_[r];
                int len = R_LEN(R);
                int off = R_OFF(R);
                for (int t = lane; t < len; t += 64) {
                    u32 v2 = pool_[off + t];
                    pool_[nb + t] = v2;
                }
                __builtin_amdgcn_wave_barrier();
                if (lane == 0) root_[r] = packRoot(R_SL(R), (int)nb, len, len);
                nb += (u32)len;
            }
        }
        bump = nb;
        halfEnd = tgt + HFS;
        curHalf ^= 1;
    };

    int lastW = -1; u64 lastPack = 0;   // register forwarding across chained merges
    for (int q = 0; q < qn; ++q) {
        u32 rec = Q_[q];
        int A  = (int)((rec >> 11) & 0x3FF);   // A = min => winner
        int B  = (int)((rec >> 21) & 0x3FF);
        u64 RA = (A == lastW) ? lastPack : root_[A];
        u64 RB = (B == lastW) ? lastPack : root_[B];
        int sLa = R_SL(RA), sLb = R_SL(RB);
        int lenA = R_LEN(RA), lenB = R_LEN(RB);
        if (bump + (u32)(lenA + lenB + 8) > halfEnd) {
            do_gc();
            lastW = -1;
            RA = root_[A]; RB = root_[B];
            lenA = R_LEN(RA); lenB = R_LEN(RB);
        }
        int offA = R_OFF(RA), capA = R_CAP(RA);
        int offB = R_OFF(RB), capB = R_CAP(RB);
        int offS, lenS, offL, lenL, capL;
        if (lenA <= lenB) { offS = offA; lenS = lenA; offL = offB; lenL = lenB; capL = capB; }
        else              { offS = offB; lenS = lenB; offL = offA; lenL = lenA; capL = capA; }
        int same = 0, dOff, dLen, dCap;

        if (lenS + lenL <= 64) {
            // register path: lists live in lanes; match via readlane+ballot
            u32 eL = (lane < lenL) ? pool_[offL + lane] : 0u;
            u32 eS = (lane < lenS) ? pool_[offS + lane] : 0u;
            dLen = lenL;
            for (int t2 = 0; t2 < lenS; ++t2) {
                u32 xs = (u32)rdl((int)eS, t2);
                bool match = (lane < lenL) && ((eL >> 16) == (xs >> 16));
                u64 mb = __ballot(match);
                if (mb) {                               // uniform branch
                    int ml = __ffsll(mb) - 1;
                    same += (int)(xs & 0xFFFF) * ((int)rdl((int)eL, ml) & 0xFFFF);
                    if (match) eL += (xs & 0xFFFF);
                } else {
                    if (lane == dLen) eL = xs;          // append to free lane
                    dLen++;
                }
            }
            if (dLen <= capL) { dOff = offL; dCap = capL; }     // in place
            else { dOff = (int)bump; dCap = (dLen + 3) & ~3; bump += (u32)dCap; }
            if (lane < dLen) pool_[dOff + lane] = eL;
        } else {
            // slow generic: stride loops + LDS histogram
            dOff = (int)bump;
            dCap = (lenL + lenS + 4) & ~3; bump += (u32)dCap;
            for (int j = lane; j < lenS; j += 64) {
                u32 es = pool_[offS + j];
                H_[es >> 16] = (short)(es & 0xFFFF);
            }
            __builtin_amdgcn_wave_barrier();
            int sp = 0;
            for (int j = lane; j < lenL; j += 64) {
                u32 el = pool_[offL + j];
                int h = (int)H_[el >> 16];
                sp += h * (int)(el & 0xFFFF);
                pool_[dOff + j] = el + (u32)h;
                if (h) H_[el >> 16] = 0;
            }
            same = wredi(sp);
            __builtin_amdgcn_wave_barrier();
            int baseU = 0;
            for (int j0 = 0; j0 < lenS; j0 += 64) {
                int j = j0 + lane;
                bool un = false; u32 es = 0;
                if (j < lenS) { es = pool_[offS + j]; un = (H_[es >> 16] != 0); }
                u64 ub = __ballot(un);
                if (un) {
                    int pos = __popcll(ub & ltm);
                    pool_[dOff + lenL + baseU + pos] = es;
                    H_[es >> 16] = 0;
                }
                baseU += __popcll(ub);
            }
            dLen = lenL + baseU;
        }
        u64 newPack = packRoot(sLa + sLb, dOff, dLen, dCap);  // uniform in all lanes
        if (lane == 0) {
            Qw_[q] = (float)(ph ? same : (sLa * sLb - same));
            root_[A] = newPack;
            root_[B] = 0;
        }
        lastW = A; lastPack = newPack;
        __builtin_amdgcn_wave_barrier();
    }

    // ---- epilogue per wave: sums over the qn recorded (merge) edges only ----
    float s_loc = 0.0f;
    for (int q = lane; q < qn; q += 64) s_loc += Qw_[q];
    const float sn = wredf(s_loc);

    const float scale = ph ? lrp_p[0] : lr_p[0];
    float acc = 0.0f;
    for (int q = lane; q < qn; q += 64) {
        float wv2 = Qw_[q];
        if (wv2 == 0.0f) continue;
        if (sn > 0.0f) wv2 /= sn;
        int me = (int)(Q_[q] & 0x7FF);
        int g = gtcL[me];
        bool zero = ph ? (g < 20) : (g >= 10);
        if (zero) continue;
        u32 ab = eab[me];
        float pa = predL[ab & 0xFFFF], pb = predL[ab >> 16];
        float fa2, fb2;
        if (ph == 0) { fa2 = pa * pa; fb2 = pb * pb; }
        else { float qa = 20.0f - pa, qb = 20.0f - pb; fa2 = qa * qa; fb2 = qb * qb; }
        acc += scale * wv2 * (fa2 + fb2);
    }
    acc = wredf(acc);
    if (lane == 0) atomicAdd(out, acc);
}

__global__ void zero_out_kernel(float* o)
{
    if (threadIdx.x == 0 && blockIdx.x == 0) o[0] = 0.0f;
}

extern "C" void kernel_launch(void* const* d_in, const int* in_sizes, int n_in,
                              void* d_out, int out_size, void* d_ws, size_t ws_size,
                              hipStream_t stream)
{
    const float* pred   = (const float*)d_in[0];
    const float* target = (const float*)d_in[1];
    const float* lr     = (const float*)d_in[2];
    const float* lrp    = (const float*)d_in[3];
    float* out = (float*)d_out;

    zero_out_kernel<<<1, 64, 0, stream>>>(out);
    malis_kernel<<<128, 128, 0, stream>>>(pred, target, lr, lrp, out);
}